// Round 1
// baseline (436.958 us; speedup 1.0000x reference)
//
#include <hip/hip_runtime.h>
#include <stdint.h>

#define D 512
#define BNROWS 8192
#define CNROWS 16384

typedef __attribute__((ext_vector_type(4))) float f32x4;
typedef __attribute__((ext_vector_type(8))) __bf16 bf16x8;

typedef const __attribute__((address_space(1))) unsigned int* gas_ptr;
typedef __attribute__((address_space(3))) unsigned int* las_ptr;

__device__ __forceinline__ void gload_lds16(const void* g, void* l) {
    __builtin_amdgcn_global_load_lds((gas_ptr)g, (las_ptr)l, 16, 0, 0);
}

// fp32 -> bf16 bits, round-to-nearest-even (finite inputs only)
__device__ __forceinline__ short f2bf(float f) {
    uint32_t u = __float_as_uint(f);
    uint32_t r = (u + 0x7FFFu + ((u >> 16) & 1u)) >> 16;
    return (short)r;
}

__device__ __forceinline__ float wave_reduce_add(float v) {
#pragma unroll
    for (int m = 32; m >= 1; m >>= 1) v += __shfl_xor(v, m, 64);
    return v;
}

// --- Kernel 1: normalize x & positive, write xn (bf16 bits), sim, zero denom ---
__global__ __launch_bounds__(256) void k_norm_xp(const float* __restrict__ x,
                                                 const float* __restrict__ p,
                                                 short* __restrict__ xnb,
                                                 float* __restrict__ sim,
                                                 float* __restrict__ denom) {
    const int wid = threadIdx.x >> 6, lane = threadIdx.x & 63;
    const int row = blockIdx.x * 4 + wid;
    const float* xr = x + (size_t)row * D + lane * 8;
    const float* pr = p + (size_t)row * D + lane * 8;
    f32x4 x0 = *(const f32x4*)xr, x1 = *(const f32x4*)(xr + 4);
    f32x4 p0 = *(const f32x4*)pr, p1 = *(const f32x4*)(pr + 4);
    float xx = 0.f, pp = 0.f, xp = 0.f;
#pragma unroll
    for (int j = 0; j < 4; ++j) {
        xx += x0[j] * x0[j] + x1[j] * x1[j];
        pp += p0[j] * p0[j] + p1[j] * p1[j];
        xp += x0[j] * p0[j] + x1[j] * p1[j];
    }
    xx = wave_reduce_add(xx);
    pp = wave_reduce_add(pp);
    xp = wave_reduce_add(xp);
    const float rx = 1.0f / fmaxf(sqrtf(xx), 1e-12f);
    const float rp = 1.0f / fmaxf(sqrtf(pp), 1e-12f);
    if (lane == 0) {
        sim[row] = xp * rx * rp;
        denom[row] = 0.0f;
    }
    typedef __attribute__((ext_vector_type(8))) short s16x8;
    s16x8 o;
#pragma unroll
    for (int j = 0; j < 4; ++j) {
        o[j] = f2bf(x0[j] * rx);
        o[j + 4] = f2bf(x1[j] * rx);
    }
    *(s16x8*)(xnb + (size_t)row * D + lane * 8) = o;
}

// --- Kernel 2: normalize negatives, write nn (bf16 bits) ---
__global__ __launch_bounds__(256) void k_norm_n(const float* __restrict__ n,
                                                short* __restrict__ nnb) {
    const int wid = threadIdx.x >> 6, lane = threadIdx.x & 63;
    const int row = blockIdx.x * 4 + wid;
    const float* nr = n + (size_t)row * D + lane * 8;
    f32x4 n0 = *(const f32x4*)nr, n1 = *(const f32x4*)(nr + 4);
    float nn = 0.f;
#pragma unroll
    for (int j = 0; j < 4; ++j) nn += n0[j] * n0[j] + n1[j] * n1[j];
    nn = wave_reduce_add(nn);
    const float rn = 1.0f / fmaxf(sqrtf(nn), 1e-12f);
    typedef __attribute__((ext_vector_type(8))) short s16x8;
    s16x8 o;
#pragma unroll
    for (int j = 0; j < 4; ++j) {
        o[j] = f2bf(n0[j] * rn);
        o[j + 4] = f2bf(n1[j] * rn);
    }
    *(s16x8*)(nnb + (size_t)row * D + lane * 8) = o;
}

// --- Kernel 3: 128x128-tile bf16 MFMA GEMM + fused exp row-sum into denom ---
// A = xn (8192 x 512, row-major, bf16 bits), B = nn (16384 x 512) ; logits = A @ B^T
// LDS layout per tile: [kg:4][row:128][8 bf16]  (kg = 8-element K-chunk)
__global__ __launch_bounds__(256) void k_gemm_exp(const short* __restrict__ A,
                                                  const short* __restrict__ B,
                                                  float* __restrict__ denom) {
    __shared__ short As[4096];  // 8 KB
    __shared__ short Bs[4096];  // 8 KB

    const int t = threadIdx.x;
    const int blockM = blockIdx.y * 128;
    const int blockN = blockIdx.x * 128;
    const int lane = t & 63;
    const int wid = t >> 6;
    const int wr = wid >> 1, wc = wid & 1;  // wave quadrant (64x64)
    const int lg = lane >> 4, lm = lane & 15;

    // staging decode: linear byte offset o -> kg = o>>11, row = (o>>4)&127
    const int o0 = t * 16;
    const int o1 = o0 + 4096;
    const int kg0 = o0 >> 11, row0 = (o0 >> 4) & 127;
    const int kg1 = o1 >> 11, row1 = (o1 >> 4) & 127;
    const char* a0 = (const char*)A + (size_t)(blockM + row0) * (D * 2) + kg0 * 16;
    const char* a1 = (const char*)A + (size_t)(blockM + row1) * (D * 2) + kg1 * 16;
    const char* b0 = (const char*)B + (size_t)(blockN + row0) * (D * 2) + kg0 * 16;
    const char* b1 = (const char*)B + (size_t)(blockN + row1) * (D * 2) + kg1 * 16;
    char* la0 = (char*)As + o0;
    char* la1 = (char*)As + o1;
    char* lb0 = (char*)Bs + o0;
    char* lb1 = (char*)Bs + o1;

    // fragment read bases: As[kg=lg][row = w*64 + mi*16 + lm][0..7]
    const short* ard = As + lg * 1024 + (wr * 64 + lm) * 8;
    const short* brd = Bs + lg * 1024 + (wc * 64 + lm) * 8;

    f32x4 acc[4][4];
#pragma unroll
    for (int i = 0; i < 4; ++i)
#pragma unroll
        for (int j = 0; j < 4; ++j) acc[i][j] = (f32x4){0.f, 0.f, 0.f, 0.f};

    for (int k0 = 0; k0 < D; k0 += 32) {
        __syncthreads();  // previous compute reads done before overwrite
        gload_lds16(a0 + k0 * 2, la0);
        gload_lds16(a1 + k0 * 2, la1);
        gload_lds16(b0 + k0 * 2, lb0);
        gload_lds16(b1 + k0 * 2, lb1);
        __syncthreads();  // vmcnt(0) drain + barrier: tile ready

        bf16x8 af[4], bfr[4];
#pragma unroll
        for (int mi = 0; mi < 4; ++mi) af[mi] = *(const bf16x8*)(ard + mi * 128);
#pragma unroll
        for (int ni = 0; ni < 4; ++ni) bfr[ni] = *(const bf16x8*)(brd + ni * 128);
#pragma unroll
        for (int mi = 0; mi < 4; ++mi)
#pragma unroll
            for (int ni = 0; ni < 4; ++ni)
                acc[mi][ni] = __builtin_amdgcn_mfma_f32_16x16x32_bf16(af[mi], bfr[ni],
                                                                      acc[mi][ni], 0, 0, 0);
    }

    // epilogue: exp + row-sum. C layout: col = lm, row = lg*4 + reg (within 16x16)
    float* drow = denom + blockM + wr * 64;
#pragma unroll
    for (int mi = 0; mi < 4; ++mi) {
#pragma unroll
        for (int r = 0; r < 4; ++r) {
            float s = 0.f;
#pragma unroll
            for (int ni = 0; ni < 4; ++ni) s += __expf(acc[mi][ni][r]);
            s += __shfl_xor(s, 1, 64);
            s += __shfl_xor(s, 2, 64);
            s += __shfl_xor(s, 4, 64);
            s += __shfl_xor(s, 8, 64);
            if (lm == 0) atomicAdd(&drow[mi * 16 + lg * 4 + r], s);
        }
    }
}

// --- Kernel 4: loss = -(sum(sim - log(denom)))/bn ---
__global__ __launch_bounds__(256) void k_final(const float* __restrict__ sim,
                                               const float* __restrict__ denom,
                                               float* __restrict__ out) {
    __shared__ float red[4];
    float s = 0.f;
    for (int i = threadIdx.x; i < BNROWS; i += 256) s += sim[i] - logf(denom[i]);
    s = wave_reduce_add(s);
    const int wid = threadIdx.x >> 6, lane = threadIdx.x & 63;
    if (lane == 0) red[wid] = s;
    __syncthreads();
    if (threadIdx.x == 0) {
        float tot = red[0] + red[1] + red[2] + red[3];
        out[0] = -tot / (float)BNROWS;
    }
}

extern "C" void kernel_launch(void* const* d_in, const int* in_sizes, int n_in,
                              void* d_out, int out_size, void* d_ws, size_t ws_size,
                              hipStream_t stream) {
    const float* x = (const float*)d_in[0];
    const float* p = (const float*)d_in[1];
    const float* n = (const float*)d_in[2];
    char* ws = (char*)d_ws;
    short* xnb = (short*)ws;                                    // 8 MB
    short* nnb = (short*)(ws + (size_t)8 * 1024 * 1024);        // 16 MB
    float* sim = (float*)(ws + (size_t)24 * 1024 * 1024);       // 32 KB
    float* denom = (float*)(ws + (size_t)24 * 1024 * 1024 + 32 * 1024);  // 32 KB
    float* out = (float*)d_out;

    k_norm_xp<<<dim3(BNROWS / 4), dim3(256), 0, stream>>>(x, p, xnb, sim, denom);
    k_norm_n<<<dim3(CNROWS / 4), dim3(256), 0, stream>>>(n, nnb);
    k_gemm_exp<<<dim3(CNROWS / 128, BNROWS / 128), dim3(256), 0, stream>>>(xnb, nnb, denom);
    k_final<<<dim3(1), dim3(256), 0, stream>>>(sim, denom, out);
}

// Round 5
// 376.293 us; speedup vs baseline: 1.1612x; 1.1612x over previous
//
#include <hip/hip_runtime.h>
#include <stdint.h>

#define D 512
#define BNROWS 8192
#define CNROWS 16384

typedef __attribute__((ext_vector_type(4))) float f32x4;
typedef __attribute__((ext_vector_type(8))) __bf16 bf16x8;
typedef __attribute__((ext_vector_type(8))) short s16x8;

typedef const __attribute__((address_space(1))) unsigned int* gas_ptr;
typedef __attribute__((address_space(3))) unsigned int* las_ptr;

__device__ __forceinline__ void gload_lds16(const void* g, void* l) {
    __builtin_amdgcn_global_load_lds((gas_ptr)g, (las_ptr)l, 16, 0, 0);
}

// fp32 -> bf16 bits, round-to-nearest-even (finite inputs only)
__device__ __forceinline__ short f2bf(float f) {
    uint32_t u = __float_as_uint(f);
    uint32_t r = (u + 0x7FFFu + ((u >> 16) & 1u)) >> 16;
    return (short)r;
}

__device__ __forceinline__ float wave_reduce_add(float v) {
#pragma unroll
    for (int m = 32; m >= 1; m >>= 1) v += __shfl_xor(v, m, 64);
    return v;
}

// --- Kernel 1: merged normalization (x&positive -> xn,sim,denom=0 ; negative -> nn) ---
__global__ __launch_bounds__(256) void k_norm(const float* __restrict__ x,
                                              const float* __restrict__ p,
                                              const float* __restrict__ n,
                                              short* __restrict__ xnb,
                                              short* __restrict__ nnb,
                                              float* __restrict__ sim,
                                              float* __restrict__ denom) {
    const int wid = threadIdx.x >> 6, lane = threadIdx.x & 63;
    if (blockIdx.x < BNROWS / 4) {
        const int row = blockIdx.x * 4 + wid;
        const float* xr = x + (size_t)row * D + lane * 8;
        const float* pr = p + (size_t)row * D + lane * 8;
        f32x4 x0 = *(const f32x4*)xr, x1 = *(const f32x4*)(xr + 4);
        f32x4 p0 = *(const f32x4*)pr, p1 = *(const f32x4*)(pr + 4);
        float xx = 0.f, pp = 0.f, xp = 0.f;
#pragma unroll
        for (int j = 0; j < 4; ++j) {
            xx += x0[j] * x0[j] + x1[j] * x1[j];
            pp += p0[j] * p0[j] + p1[j] * p1[j];
            xp += x0[j] * p0[j] + x1[j] * p1[j];
        }
        xx = wave_reduce_add(xx);
        pp = wave_reduce_add(pp);
        xp = wave_reduce_add(xp);
        const float rx = 1.0f / fmaxf(sqrtf(xx), 1e-12f);
        const float rp = 1.0f / fmaxf(sqrtf(pp), 1e-12f);
        if (lane == 0) {
            sim[row] = xp * rx * rp;
            denom[row] = 0.0f;
        }
        s16x8 o;
#pragma unroll
        for (int j = 0; j < 4; ++j) {
            o[j] = f2bf(x0[j] * rx);
            o[j + 4] = f2bf(x1[j] * rx);
        }
        *(s16x8*)(xnb + (size_t)row * D + lane * 8) = o;
    } else {
        const int row = (blockIdx.x - BNROWS / 4) * 4 + wid;
        const float* nr = n + (size_t)row * D + lane * 8;
        f32x4 n0 = *(const f32x4*)nr, n1 = *(const f32x4*)(nr + 4);
        float nn = 0.f;
#pragma unroll
        for (int j = 0; j < 4; ++j) nn += n0[j] * n0[j] + n1[j] * n1[j];
        nn = wave_reduce_add(nn);
        const float rn = 1.0f / fmaxf(sqrtf(nn), 1e-12f);
        s16x8 o;
#pragma unroll
        for (int j = 0; j < 4; ++j) {
            o[j] = f2bf(n0[j] * rn);
            o[j + 4] = f2bf(n1[j] * rn);
        }
        *(s16x8*)(nnb + (size_t)row * D + lane * 8) = o;
    }
}

// --- Kernel 2: 256x256-tile, BK=64, 8-wave, 8-phase pipelined bf16 MFMA GEMM
//     + fused exp row-sum into denom.  A = xn (8192x512), B = nn (16384x512),
//     logits = A @ B^T.  LDS: [buf:2][mat:2][half:2][kg:8][row:128][8 bf16] = 128 KiB.
//     Per-phase: {ds_read subtile || stage 1 half-tile} -> s_barrier -> lgkmcnt(0)
//     -> setprio(1) 16xMFMA setprio(0) -> [vmcnt(4) at tile boundary] -> s_barrier.
//     Staging lead: A-halves of tile t+1 at phases 0/1, B-halves of t+2 at 2/3,
//     A of t+2 at 4/5, B of t+3 at 6/7. Each region freed >=1 barrier before reuse.

#define LOAD_A(buf, mh)                                                                  \
    {                                                                                    \
        _Pragma("unroll") for (int m2 = 0; m2 < 4; ++m2) _Pragma("unroll") for (int ks = \
                                                                                    0;   \
                                                                                ks < 2;  \
                                                                                ++ks)    \
            af[m2 * 2 + ks] =                                                            \
            *(const bf16x8*)(Ard[buf] + (mh)*512 + m2 * 128 + ks * 4096);                \
    }
#define LOAD_B(buf, nh)                                                                  \
    {                                                                                    \
        _Pragma("unroll") for (int n2 = 0; n2 < 2; ++n2) _Pragma("unroll") for (int ks = \
                                                                                    0;   \
                                                                                ks < 2;  \
                                                                                ++ks)    \
            bfr[((nh)*2 + n2) * 2 + ks] =                                                \
            *(const bf16x8*)(Brd[buf] + ((nh)*2 + n2) * 128 + ks * 4096);                \
    }
#define MMA(mh, nh)                                                                     \
    {                                                                                   \
        _Pragma("unroll") for (int m2 = 0; m2 < 4; ++m2)                                \
            _Pragma("unroll") for (int n2 = 0; n2 < 2; ++n2)                            \
                _Pragma("unroll") for (int ks = 0; ks < 2; ++ks) acc[(mh)*4 + m2]       \
                                                                   [(nh)*2 + n2] =     \
                __builtin_amdgcn_mfma_f32_16x16x32_bf16(af[m2 * 2 + ks],                \
                                                        bfr[((nh)*2 + n2) * 2 + ks],   \
                                                        acc[(mh)*4 + m2][(nh)*2 + n2], \
                                                        0, 0, 0);                      \
    }
#define STAGE_A(buf, h, kt)                                      \
    {                                                            \
        gload_lds16(agp[h] + (kt)*64, dstA[buf][h]);             \
        gload_lds16(agp[h] + (kt)*64 + 32, dstA[buf][h] + 4096); \
    }
#define STAGE_B(buf, h, kt)                                      \
    {                                                            \
        gload_lds16(bgp[h] + (kt)*64, dstB[buf][h]);             \
        gload_lds16(bgp[h] + (kt)*64 + 32, dstB[buf][h] + 4096); \
    }
#define BAR() __builtin_amdgcn_s_barrier()
#define LGKM0() asm volatile("s_waitcnt lgkmcnt(0)" ::: "memory")
#define PRIO1() __builtin_amdgcn_s_setprio(1)
#define PRIO0() __builtin_amdgcn_s_setprio(0)
#define VMC4() asm volatile("s_waitcnt vmcnt(4)" ::: "memory")
#define VMC0() asm volatile("s_waitcnt vmcnt(0)" ::: "memory")

// One iteration = 2 K-tiles (t0 even -> buf0, t0+1 -> buf1), 8 phases.
#define ITER(t0, ST)                                                                 \
    {                                                                                \
        /*P0*/ LOAD_A(0, 0); LOAD_B(0, 0); STAGE_A(1, 0, (t0) + 1);                  \
        BAR(); LGKM0(); PRIO1(); MMA(0, 0); PRIO0(); BAR();                          \
        /*P1*/ LOAD_B(0, 1); STAGE_A(1, 1, (t0) + 1);                                \
        BAR(); LGKM0(); PRIO1(); MMA(0, 1); PRIO0(); BAR();                          \
        /*P2*/ LOAD_A(0, 1); if (ST) STAGE_B(0, 0, (t0) + 2);                        \
        BAR(); LGKM0(); PRIO1(); MMA(1, 0); PRIO0(); BAR();                          \
        /*P3*/ if (ST) STAGE_B(0, 1, (t0) + 2);                                      \
        BAR(); PRIO1(); MMA(1, 1); PRIO0();                                          \
        if (ST) VMC4(); else VMC0();                                                 \
        BAR();                                                                       \
        /*P4*/ LOAD_A(1, 0); LOAD_B(1, 0); if (ST) STAGE_A(0, 0, (t0) + 2);          \
        BAR(); LGKM0(); PRIO1(); MMA(0, 0); PRIO0(); BAR();                          \
        /*P5*/ LOAD_B(1, 1); if (ST) STAGE_A(0, 1, (t0) + 2);                        \
        BAR(); LGKM0(); PRIO1(); MMA(0, 1); PRIO0(); BAR();                          \
        /*P6*/ LOAD_A(1, 1); if (ST) STAGE_B(1, 0, (t0) + 3);                        \
        BAR(); LGKM0(); PRIO1(); MMA(1, 0); PRIO0(); BAR();                          \
        /*P7*/ if (ST) STAGE_B(1, 1, (t0) + 3);                                      \
        BAR(); PRIO1(); MMA(1, 1); PRIO0();                                          \
        if (ST) VMC4();                                                              \
        BAR();                                                                       \
    }

__global__ __launch_bounds__(512, 2) void k_gemm_exp(const short* __restrict__ A,
                                                     const short* __restrict__ B,
                                                     float* __restrict__ denom) {
    __shared__ short lds[2][2][2][8][128][8];  // 128 KiB

    const int t = threadIdx.x;
    const int lane = t & 63, wid = t >> 6;
    const int wr = wid >> 2, wc = wid & 3;  // 2x4 wave grid, per-wave C = 128x64
    const int lg = lane >> 4, lm = lane & 15;
    const int blockM = blockIdx.y * 256;
    const int blockN = blockIdx.x * 256;

    // staging: thread t stages row (t&127), kg (t>>7) and kg+4 of each half-tile
    const int row_s = t & 127, kg_s = t >> 7;
    const short* agp[2];
    const short* bgp[2];
    short* dstA[2][2];
    short* dstB[2][2];
#pragma unroll
    for (int h = 0; h < 2; ++h) {
        agp[h] = A + (size_t)(blockM + h * 128 + row_s) * D + kg_s * 8;
        bgp[h] = B + (size_t)(blockN + h * 128 + row_s) * D + kg_s * 8;
#pragma unroll
        for (int buf = 0; buf < 2; ++buf) {
            dstA[buf][h] = &lds[buf][0][h][kg_s][row_s][0];
            dstB[buf][h] = &lds[buf][1][h][kg_s][row_s][0];
        }
    }
    // fragment read bases (conflict-free: 16 lm-lanes span 256 contiguous bytes)
    const short* Ard[2];
    const short* Brd[2];
#pragma unroll
    for (int buf = 0; buf < 2; ++buf) {
        Ard[buf] = &lds[buf][0][wr][lg][lm][0];
        Brd[buf] = &lds[buf][1][wc >> 1][lg][(wc & 1) * 64 + lm][0];
    }

    f32x4 acc[8][4];
#pragma unroll
    for (int i = 0; i < 8; ++i)
#pragma unroll
        for (int j = 0; j < 4; ++j) acc[i][j] = (f32x4){0.f, 0.f, 0.f, 0.f};

    bf16x8 af[8], bfr[8];

    // prologue: tile0 (A+B) -> buf0, tile1 B -> buf1 (tile1 A staged at P0/P1)
    STAGE_A(0, 0, 0);
    STAGE_A(0, 1, 0);
    STAGE_B(0, 0, 0);
    STAGE_B(0, 1, 0);
    STAGE_B(1, 0, 1);
    STAGE_B(1, 1, 1);
    VMC4();  // tile0's 8 loads landed; tile1's 4 B-loads may remain in flight
    BAR();

    for (int i = 0; i < 3; ++i) {
        const int t0 = 2 * i;
        ITER(t0, 1);
    }
    ITER(6, 0);

    // epilogue: exp + row-sum (C frag: col = lm, row = lg*4 + r within 16x16)
    float* drow = denom + blockM + wr * 128;
#pragma unroll
    for (int mi = 0; mi < 8; ++mi) {
#pragma unroll
        for (int r = 0; r < 4; ++r) {
            float s = 0.f;
#pragma unroll
            for (int ni = 0; ni < 4; ++ni) s += __expf(acc[mi][ni][r]);
            s += __shfl_xor(s, 1, 64);
            s += __shfl_xor(s, 2, 64);
            s += __shfl_xor(s, 4, 64);
            s += __shfl_xor(s, 8, 64);
            if (lm == 0) atomicAdd(&drow[mi * 16 + lg * 4 + r], s);
        }
    }
}

// --- Kernel 3: loss = -(sum(sim - log(denom)))/bn ---
__global__ __launch_bounds__(256) void k_final(const float* __restrict__ sim,
                                               const float* __restrict__ denom,
                                               float* __restrict__ out) {
    __shared__ float red[4];
    float s = 0.f;
    for (int i = threadIdx.x; i < BNROWS; i += 256) s += sim[i] - logf(denom[i]);
    s = wave_reduce_add(s);
    const int wid = threadIdx.x >> 6, lane = threadIdx.x & 63;
    if (lane == 0) red[wid] = s;
    __syncthreads();
    if (threadIdx.x == 0) {
        float tot = red[0] + red[1] + red[2] + red[3];
        out[0] = -tot / (float)BNROWS;
    }
}

extern "C" void kernel_launch(void* const* d_in, const int* in_sizes, int n_in,
                              void* d_out, int out_size, void* d_ws, size_t ws_size,
                              hipStream_t stream) {
    const float* x = (const float*)d_in[0];
    const float* p = (const float*)d_in[1];
    const float* n = (const float*)d_in[2];
    char* ws = (char*)d_ws;
    short* xnb = (short*)ws;                                             // 8 MB
    short* nnb = (short*)(ws + (size_t)8 * 1024 * 1024);                 // 16 MB
    float* sim = (float*)(ws + (size_t)24 * 1024 * 1024);                // 32 KB
    float* denom = (float*)(ws + (size_t)24 * 1024 * 1024 + 32 * 1024);  // 32 KB
    float* out = (float*)d_out;

    k_norm<<<dim3(BNROWS / 4 + CNROWS / 4), dim3(256), 0, stream>>>(x, p, n, xnb, nnb,
                                                                    sim, denom);
    k_gemm_exp<<<dim3(CNROWS / 256, BNROWS / 256), dim3(512), 0, stream>>>(xnb, nnb,
                                                                           denom);
    k_final<<<dim3(1), dim3(256), 0, stream>>>(sim, denom, out);
}

// Round 6
// 283.708 us; speedup vs baseline: 1.5402x; 1.3263x over previous
//
#include <hip/hip_runtime.h>
#include <stdint.h>

#define D 512
#define BNROWS 8192
#define CNROWS 16384
#define NPART 256  // partial-denom columns: 64 blockIdx.x * 4 wc-waves

typedef __attribute__((ext_vector_type(4))) float f32x4;
typedef __attribute__((ext_vector_type(8))) __bf16 bf16x8;
typedef __attribute__((ext_vector_type(8))) short s16x8;

typedef const __attribute__((address_space(1))) unsigned int* gas_ptr;
typedef __attribute__((address_space(3))) unsigned int* las_ptr;

__device__ __forceinline__ void gload_lds16(const void* g, void* l) {
    __builtin_amdgcn_global_load_lds((gas_ptr)g, (las_ptr)l, 16, 0, 0);
}

// fp32 -> bf16 bits, round-to-nearest-even (finite inputs only)
__device__ __forceinline__ short f2bf(float f) {
    uint32_t u = __float_as_uint(f);
    uint32_t r = (u + 0x7FFFu + ((u >> 16) & 1u)) >> 16;
    return (short)r;
}

__device__ __forceinline__ float wave_reduce_add(float v) {
#pragma unroll
    for (int m = 32; m >= 1; m >>= 1) v += __shfl_xor(v, m, 64);
    return v;
}

// --- Kernel 1: merged normalization (x&positive -> xn,sim ; negative -> nn) ---
__global__ __launch_bounds__(256) void k_norm(const float* __restrict__ x,
                                              const float* __restrict__ p,
                                              const float* __restrict__ n,
                                              short* __restrict__ xnb,
                                              short* __restrict__ nnb,
                                              float* __restrict__ sim) {
    const int wid = threadIdx.x >> 6, lane = threadIdx.x & 63;
    if (blockIdx.x < BNROWS / 4) {
        const int row = blockIdx.x * 4 + wid;
        const float* xr = x + (size_t)row * D + lane * 8;
        const float* pr = p + (size_t)row * D + lane * 8;
        f32x4 x0 = *(const f32x4*)xr, x1 = *(const f32x4*)(xr + 4);
        f32x4 p0 = *(const f32x4*)pr, p1 = *(const f32x4*)(pr + 4);
        float xx = 0.f, pp = 0.f, xp = 0.f;
#pragma unroll
        for (int j = 0; j < 4; ++j) {
            xx += x0[j] * x0[j] + x1[j] * x1[j];
            pp += p0[j] * p0[j] + p1[j] * p1[j];
            xp += x0[j] * p0[j] + x1[j] * p1[j];
        }
        xx = wave_reduce_add(xx);
        pp = wave_reduce_add(pp);
        xp = wave_reduce_add(xp);
        const float rx = 1.0f / fmaxf(sqrtf(xx), 1e-12f);
        const float rp = 1.0f / fmaxf(sqrtf(pp), 1e-12f);
        if (lane == 0) sim[row] = xp * rx * rp;
        s16x8 o;
#pragma unroll
        for (int j = 0; j < 4; ++j) {
            o[j] = f2bf(x0[j] * rx);
            o[j + 4] = f2bf(x1[j] * rx);
        }
        *(s16x8*)(xnb + (size_t)row * D + lane * 8) = o;
    } else {
        const int row = (blockIdx.x - BNROWS / 4) * 4 + wid;
        const float* nr = n + (size_t)row * D + lane * 8;
        f32x4 n0 = *(const f32x4*)nr, n1 = *(const f32x4*)(nr + 4);
        float nn = 0.f;
#pragma unroll
        for (int j = 0; j < 4; ++j) nn += n0[j] * n0[j] + n1[j] * n1[j];
        nn = wave_reduce_add(nn);
        const float rn = 1.0f / fmaxf(sqrtf(nn), 1e-12f);
        s16x8 o;
#pragma unroll
        for (int j = 0; j < 4; ++j) {
            o[j] = f2bf(n0[j] * rn);
            o[j + 4] = f2bf(n1[j] * rn);
        }
        *(s16x8*)(nnb + (size_t)row * D + lane * 8) = o;
    }
}

// --- Kernel 2: 256x256-tile, BK=64, 8-wave, 8-phase pipelined bf16 MFMA GEMM
//     + fused exp row-sum -> NON-ATOMIC per-(block,wc) partial stores.
//     Identical K-loop/schedule to round-5; only the epilogue changed
//     (atomicAdd -> plain store into part[row][bx*4+wc]).

#define LOAD_A(buf, mh)                                                                  \
    {                                                                                    \
        _Pragma("unroll") for (int m2 = 0; m2 < 4; ++m2) _Pragma("unroll") for (int ks = \
                                                                                    0;   \
                                                                                ks < 2;  \
                                                                                ++ks)    \
            af[m2 * 2 + ks] =                                                            \
            *(const bf16x8*)(Ard[buf] + (mh)*512 + m2 * 128 + ks * 4096);                \
    }
#define LOAD_B(buf, nh)                                                                  \
    {                                                                                    \
        _Pragma("unroll") for (int n2 = 0; n2 < 2; ++n2) _Pragma("unroll") for (int ks = \
                                                                                    0;   \
                                                                                ks < 2;  \
                                                                                ++ks)    \
            bfr[((nh)*2 + n2) * 2 + ks] =                                                \
            *(const bf16x8*)(Brd[buf] + ((nh)*2 + n2) * 128 + ks * 4096);                \
    }
#define MMA(mh, nh)                                                                     \
    {                                                                                   \
        _Pragma("unroll") for (int m2 = 0; m2 < 4; ++m2)                                \
            _Pragma("unroll") for (int n2 = 0; n2 < 2; ++n2)                            \
                _Pragma("unroll") for (int ks = 0; ks < 2; ++ks) acc[(mh)*4 + m2]       \
                                                                   [(nh)*2 + n2] =     \
                __builtin_amdgcn_mfma_f32_16x16x32_bf16(af[m2 * 2 + ks],                \
                                                        bfr[((nh)*2 + n2) * 2 + ks],   \
                                                        acc[(mh)*4 + m2][(nh)*2 + n2], \
                                                        0, 0, 0);                      \
    }
#define STAGE_A(buf, h, kt)                                      \
    {                                                            \
        gload_lds16(agp[h] + (kt)*64, dstA[buf][h]);             \
        gload_lds16(agp[h] + (kt)*64 + 32, dstA[buf][h] + 4096); \
    }
#define STAGE_B(buf, h, kt)                                      \
    {                                                            \
        gload_lds16(bgp[h] + (kt)*64, dstB[buf][h]);             \
        gload_lds16(bgp[h] + (kt)*64 + 32, dstB[buf][h] + 4096); \
    }
#define BAR() __builtin_amdgcn_s_barrier()
#define LGKM0() asm volatile("s_waitcnt lgkmcnt(0)" ::: "memory")
#define PRIO1() __builtin_amdgcn_s_setprio(1)
#define PRIO0() __builtin_amdgcn_s_setprio(0)
#define VMC4() asm volatile("s_waitcnt vmcnt(4)" ::: "memory")
#define VMC0() asm volatile("s_waitcnt vmcnt(0)" ::: "memory")

// One iteration = 2 K-tiles (t0 even -> buf0, t0+1 -> buf1), 8 phases.
#define ITER(t0, ST)                                                                 \
    {                                                                                \
        /*P0*/ LOAD_A(0, 0); LOAD_B(0, 0); STAGE_A(1, 0, (t0) + 1);                  \
        BAR(); LGKM0(); PRIO1(); MMA(0, 0); PRIO0(); BAR();                          \
        /*P1*/ LOAD_B(0, 1); STAGE_A(1, 1, (t0) + 1);                                \
        BAR(); LGKM0(); PRIO1(); MMA(0, 1); PRIO0(); BAR();                          \
        /*P2*/ LOAD_A(0, 1); if (ST) STAGE_B(0, 0, (t0) + 2);                        \
        BAR(); LGKM0(); PRIO1(); MMA(1, 0); PRIO0(); BAR();                          \
        /*P3*/ if (ST) STAGE_B(0, 1, (t0) + 2);                                      \
        BAR(); PRIO1(); MMA(1, 1); PRIO0();                                          \
        if (ST) VMC4(); else VMC0();                                                 \
        BAR();                                                                       \
        /*P4*/ LOAD_A(1, 0); LOAD_B(1, 0); if (ST) STAGE_A(0, 0, (t0) + 2);          \
        BAR(); LGKM0(); PRIO1(); MMA(0, 0); PRIO0(); BAR();                          \
        /*P5*/ LOAD_B(1, 1); if (ST) STAGE_A(0, 1, (t0) + 2);                        \
        BAR(); LGKM0(); PRIO1(); MMA(0, 1); PRIO0(); BAR();                          \
        /*P6*/ LOAD_A(1, 1); if (ST) STAGE_B(1, 0, (t0) + 3);                        \
        BAR(); LGKM0(); PRIO1(); MMA(1, 0); PRIO0(); BAR();                          \
        /*P7*/ if (ST) STAGE_B(1, 1, (t0) + 3);                                      \
        BAR(); PRIO1(); MMA(1, 1); PRIO0();                                          \
        if (ST) VMC4();                                                              \
        BAR();                                                                       \
    }

__global__ __launch_bounds__(512, 2) void k_gemm_exp(const short* __restrict__ A,
                                                     const short* __restrict__ B,
                                                     float* __restrict__ part) {
    __shared__ short lds[2][2][2][8][128][8];  // 128 KiB

    const int t = threadIdx.x;
    const int lane = t & 63, wid = t >> 6;
    const int wr = wid >> 2, wc = wid & 3;  // 2x4 wave grid, per-wave C = 128x64
    const int lg = lane >> 4, lm = lane & 15;
    const int blockM = blockIdx.y * 256;
    const int blockN = blockIdx.x * 256;

    // staging: thread t stages row (t&127), kg (t>>7) and kg+4 of each half-tile
    const int row_s = t & 127, kg_s = t >> 7;
    const short* agp[2];
    const short* bgp[2];
    short* dstA[2][2];
    short* dstB[2][2];
#pragma unroll
    for (int h = 0; h < 2; ++h) {
        agp[h] = A + (size_t)(blockM + h * 128 + row_s) * D + kg_s * 8;
        bgp[h] = B + (size_t)(blockN + h * 128 + row_s) * D + kg_s * 8;
#pragma unroll
        for (int buf = 0; buf < 2; ++buf) {
            dstA[buf][h] = &lds[buf][0][h][kg_s][row_s][0];
            dstB[buf][h] = &lds[buf][1][h][kg_s][row_s][0];
        }
    }
    // fragment read bases (conflict-free: 16 lm-lanes span 256 contiguous bytes)
    const short* Ard[2];
    const short* Brd[2];
#pragma unroll
    for (int buf = 0; buf < 2; ++buf) {
        Ard[buf] = &lds[buf][0][wr][lg][lm][0];
        Brd[buf] = &lds[buf][1][wc >> 1][lg][(wc & 1) * 64 + lm][0];
    }

    f32x4 acc[8][4];
#pragma unroll
    for (int i = 0; i < 8; ++i)
#pragma unroll
        for (int j = 0; j < 4; ++j) acc[i][j] = (f32x4){0.f, 0.f, 0.f, 0.f};

    bf16x8 af[8], bfr[8];

    // prologue: tile0 (A+B) -> buf0, tile1 B -> buf1 (tile1 A staged at P0/P1)
    STAGE_A(0, 0, 0);
    STAGE_A(0, 1, 0);
    STAGE_B(0, 0, 0);
    STAGE_B(0, 1, 0);
    STAGE_B(1, 0, 1);
    STAGE_B(1, 1, 1);
    VMC4();  // tile0's 8 loads landed; tile1's 4 B-loads may remain in flight
    BAR();

    for (int i = 0; i < 3; ++i) {
        const int t0 = 2 * i;
        ITER(t0, 1);
    }
    ITER(6, 0);

    // epilogue: exp + row-sum (C frag: col = lm, row = lg*4 + r within 16x16).
    // NON-ATOMIC: each (block, wc) owns column bx*4+wc of part[8192][256].
    const int pcol = blockIdx.x * 4 + wc;
    float* prow = part + (size_t)(blockM + wr * 128) * NPART + pcol;
#pragma unroll
    for (int mi = 0; mi < 8; ++mi) {
#pragma unroll
        for (int r = 0; r < 4; ++r) {
            float s = 0.f;
#pragma unroll
            for (int ni = 0; ni < 4; ++ni) s += __expf(acc[mi][ni][r]);
            s += __shfl_xor(s, 1, 64);
            s += __shfl_xor(s, 2, 64);
            s += __shfl_xor(s, 4, 64);
            s += __shfl_xor(s, 8, 64);
            if (lm == 0) prow[(size_t)(mi * 16 + lg * 4 + r) * NPART] = s;
        }
    }
}

// --- Kernel 3a: per-row denom = sum(part[row][0..255]); term = sim - log(denom);
//     block-partial term sums -> bterm[2048] (no atomics) ---
__global__ __launch_bounds__(256) void k_final1(const float* __restrict__ part,
                                                const float* __restrict__ sim,
                                                float* __restrict__ bterm) {
    __shared__ float red[4];
    const int wid = threadIdx.x >> 6, lane = threadIdx.x & 63;
    const int row = blockIdx.x * 4 + wid;
    f32x4 v = *(const f32x4*)(part + (size_t)row * NPART + lane * 4);
    float s = v[0] + v[1] + v[2] + v[3];
    s = wave_reduce_add(s);
    float term = 0.f;
    if (lane == 0) term = sim[row] - logf(s);
    if (lane == 0) red[wid] = term;
    __syncthreads();
    if (threadIdx.x == 0)
        bterm[blockIdx.x] = red[0] + red[1] + red[2] + red[3];
}

// --- Kernel 3b: loss = -(sum bterm)/bn ---
__global__ __launch_bounds__(256) void k_final2(const float* __restrict__ bterm,
                                                float* __restrict__ out) {
    __shared__ float red[4];
    float s = 0.f;
    for (int i = threadIdx.x; i < BNROWS / 4; i += 256) s += bterm[i];
    s = wave_reduce_add(s);
    const int wid = threadIdx.x >> 6, lane = threadIdx.x & 63;
    if (lane == 0) red[wid] = s;
    __syncthreads();
    if (threadIdx.x == 0) {
        float tot = red[0] + red[1] + red[2] + red[3];
        out[0] = -tot / (float)BNROWS;
    }
}

extern "C" void kernel_launch(void* const* d_in, const int* in_sizes, int n_in,
                              void* d_out, int out_size, void* d_ws, size_t ws_size,
                              hipStream_t stream) {
    const float* x = (const float*)d_in[0];
    const float* p = (const float*)d_in[1];
    const float* n = (const float*)d_in[2];
    char* ws = (char*)d_ws;
    short* xnb = (short*)ws;                                              // 8 MB
    short* nnb = (short*)(ws + (size_t)8 * 1024 * 1024);                  // 16 MB
    float* sim = (float*)(ws + (size_t)24 * 1024 * 1024);                 // 32 KB
    float* part = (float*)(ws + (size_t)24 * 1024 * 1024 + 64 * 1024);    // 8 MB
    float* bterm = (float*)(ws + (size_t)33 * 1024 * 1024);               // 8 KB
    float* out = (float*)d_out;

    k_norm<<<dim3(BNROWS / 4 + CNROWS / 4), dim3(256), 0, stream>>>(x, p, n, xnb, nnb,
                                                                    sim);
    k_gemm_exp<<<dim3(CNROWS / 256, BNROWS / 256), dim3(512), 0, stream>>>(xnb, nnb,
                                                                           part);
    k_final1<<<dim3(BNROWS / 4), dim3(256), 0, stream>>>(part, sim, bterm);
    k_final2<<<dim3(1), dim3(256), 0, stream>>>(bterm, out);
}